// Round 13
// baseline (4274.486 us; speedup 1.0000x reference)
//
#include <hip/hip_runtime.h>
#include <hip/hip_bf16.h>

// B=64, S=2048, WIN=50, E=128, H=256, G=4H=1024.
#define B_ 64
#define S_ 2048
#define W_ 50
#define E_ 128
#define H_ 256
#define G_ 1024

typedef unsigned short u16;
typedef unsigned int u32;
typedef unsigned char u8;
typedef unsigned int v4u __attribute__((ext_vector_type(4)));
typedef __attribute__((ext_vector_type(8))) short short8;   // bf16x8 MFMA frag
typedef __attribute__((ext_vector_type(4))) float f32x4;    // MFMA acc

// Module-global scratch (BSS; d_ws untrusted).
__device__ int g_mode;                          // 0 = bf16 buffers, 1 = fp32 buffers
__device__ u16 g_WA[E_ * G_];                   // Wih in MFMA A-frag order (bf16) [r3-validated]
__device__ float g_bias[G_];                    // bih+bhh, gate-interleaved c = 4u+q
__device__ u32 g_Wi8[G_ * 64];                  // [u][j][g]: pack4(Whh col c=4u+g, k=4j..4j+3)
__device__ float g_wscale[G_];                  // per-column dequant: max|W[:,c]| /(127*127), c=4u+g
__device__ u16 g_xg[(size_t)B_ * S_ * G_];      // [b][s][1024] bf16, biases folded (validated)
__device__ float g_hs[(size_t)B_ * S_ * H_];    // [b][s][u] fp32 hidden states (for output head)

__device__ __forceinline__ float b2f(u16 u) {
    union { u32 i; float f; } v;
    v.i = ((u32)u) << 16;
    return v.f;
}
__device__ __forceinline__ u16 f2b(float f) {
    __hip_bfloat16 h = __float2bfloat16(f);
    return *reinterpret_cast<u16*>(&h);
}
__device__ __forceinline__ float ldin(int mode, const void* p, size_t i) {
    return mode ? ((const float*)p)[i] : b2f(((const u16*)p)[i]);
}
__device__ __forceinline__ float clamp30(float x) {
    return fminf(fmaxf(x, -30.0f), 30.0f);
}
__device__ __forceinline__ float sigmoidf_(float x) { return 1.0f / (1.0f + __expf(-x)); }
__device__ __forceinline__ float tanhf_(float x) {
    float e = __expf(2.0f * x);
    return 1.0f - 2.0f / (e + 1.0f);
}
// Fast forms for the lstm hot loop ONLY (r10-validated): v_rcp_f32 (<=1 ulp)
// replaces the IEEE divide chain; rcp(inf)=0 gives exact saturation -> no clamp.
__device__ __forceinline__ float fastrcp(float x) {
    float r;
    asm("v_rcp_f32 %0, %1" : "=v"(r) : "v"(x));
    return r;
}
__device__ __forceinline__ float fsig(float x) { return fastrcp(1.0f + __expf(-x)); }
__device__ __forceinline__ float ftanh(float x) {
    return fmaf(-2.0f, fastrcp(1.0f + __expf(2.0f * x)), 1.0f);
}
// r11-validated: lane^1 pair-combine as VALU DPP (quad_perm [1,0,3,2] = 0xB1).
__device__ __forceinline__ int dppadd1(int x) {
    return x + __builtin_amdgcn_update_dpp(0, x, 0xB1, 0xF, 0xF, true);
}
__device__ __forceinline__ int dot4i8(u32 a, u32 b, int acc) {
#if __has_builtin(__builtin_amdgcn_sdot4)
    return __builtin_amdgcn_sdot4(a, b, acc, false);
#else
    acc += (int)(signed char)(a)       * (int)(signed char)(b);
    acc += (int)(signed char)(a >> 8)  * (int)(signed char)(b >> 8);
    acc += (int)(signed char)(a >> 16) * (int)(signed char)(b >> 16);
    acc += (int)(signed char)(a >> 24) * (int)(signed char)(b >> 24);
    return acc;
#endif
}

// ---------- K0: dtype sniffer (validated) ----------
__global__ void sniff_kernel(const u16* __restrict__ wemb) {
    int sane = 0;
    for (int i = 0; i < 2048; ++i) {
        int ex = (wemb[i] >> 7) & 0xFF;
        if (ex == 0 || (ex >= 96 && ex <= 143)) ++sane;
    }
    g_mode = (sane >= 1900) ? 0 : 1;
}

// ---------- K0b: Wih -> MFMA A-fragment order (r3-validated) ----------
__global__ __launch_bounds__(256) void prep_wa(const void* __restrict__ src) {
    const int mode = g_mode;
    int i = blockIdx.x * 256 + threadIdx.x;          // dst flat index, 0..131071
    int j = i & 7, l = (i >> 3) & 63, ks = (i >> 9) & 3, ct = i >> 11;
    int c = ct * 16 + (l & 15);
    int e = ks * 32 + (l >> 4) * 8 + j;
    int row = ((c & 3) << 8) + (c >> 2);
    g_WA[i] = f2b(ldin(mode, src, (size_t)row * E_ + e));
}

// ---------- K0c: Whh -> int8, unit-major quad layout [u][j][g]; + gate biases ----------
__global__ __launch_bounds__(256) void prep_wi8(const void* __restrict__ src,
                                                const void* __restrict__ bih,
                                                const void* __restrict__ bhh) {
    const int mode = g_mode;
    int c = blockIdx.x * 256 + threadIdx.x;          // c = 4u+g, 0..1023
    int row = ((c & 3) << 8) + (c >> 2);             // gate*256 + unit (validated)
    g_bias[c] = ldin(mode, bih, row) + ldin(mode, bhh, row);
    const size_t base = (size_t)row * H_;
    float m = 0.0f;
    for (int k = 0; k < H_; ++k) m = fmaxf(m, fabsf(ldin(mode, src, base + k)));
    float inv = (m > 0.0f) ? 127.0f / m : 0.0f;
    g_wscale[c] = m / (127.0f * 127.0f);             // w-scale * h-scale(1/127)
    for (int j = 0; j < 64; ++j) {
        u32 pk = 0;
#pragma unroll
        for (int i = 0; i < 4; ++i) {
            int q = (int)rintf(ldin(mode, src, base + 4 * j + i) * inv);
            q = max(-127, min(127, q));
            pk |= ((u32)(q & 0xff)) << (8 * i);
        }
        g_Wi8[(size_t)(c >> 2) * 256 + j * 4 + (c & 3)] = pk;
    }
}

// ---------- K1: fused embedding + input projection (MFMA, 64-row blocks, r9-validated) ----------
__global__ __launch_bounds__(256) void xg_mfma(const void* __restrict__ pw,
                                               const void* __restrict__ Wemb,
                                               const void* __restrict__ bemb) {
    const int mode = g_mode;
    const int t = threadIdx.x;
    const int m0 = blockIdx.x * 64;
    __shared__ float pwS[64][W_ + 2];                // 13.3 KB
    __shared__ float Wl[E_ * 51];                    // 26 KB
    __shared__ __align__(16) u16 embL[64][136];      // 17.4 KB   (total ~56.7 KB)

    for (int i = t; i < E_ * W_; i += 256) {
        int e = i / W_, w = i - e * W_;
        Wl[e * 51 + w] = ldin(mode, Wemb, i);
    }
    for (int i = t; i < 64 * W_; i += 256) {
        int r = i / W_, w = i - r * W_;
        pwS[r][w] = ldin(mode, pw, (size_t)(m0 + r) * W_ + w);
    }
    __syncthreads();

    {   // emb: e = t&127 constant per thread; W-row cached in regs (r8-validated)
        const int e = t & 127;
        float wreg[W_];
#pragma unroll
        for (int w = 0; w < W_; ++w) wreg[w] = Wl[e * 51 + w];
        const float bb = ldin(mode, bemb, e);
#pragma unroll
        for (int i = 0; i < 32; ++i) {
            const int r = i * 2 + (t >> 7);          // covers all 64 rows x 128 cols
            float a = bb;
#pragma unroll
            for (int w = 0; w < W_; ++w) a = fmaf(pwS[r][w], wreg[w], a);
            embL[r][e] = f2b(fmaxf(a, 0.0f));
        }
    }
    __syncthreads();

    const int l = t & 63;
    const int wv = t >> 6;                           // wave id 0..3 -> 256 c-cols each
    const int lr = l & 15;                           // B-col / D-col within tile
    const int lh = l >> 4;
    short8 Bf[4][4];
#pragma unroll
    for (int rg = 0; rg < 4; ++rg)
#pragma unroll
        for (int ks = 0; ks < 4; ++ks)
            Bf[rg][ks] = *(const short8*)&embL[rg * 16 + lr][ks * 32 + lh * 8];

    const short8* wa = (const short8*)g_WA;
#pragma unroll 2
    for (int tt = 0; tt < 16; ++tt) {
        const int ct = wv * 16 + tt;                 // c-tile index 0..63
        const int cbase = ct * 16;
        const short8 A0 = wa[(ct * 4 + 0) * 64 + l];
        const short8 A1 = wa[(ct * 4 + 1) * 64 + l];
        const short8 A2 = wa[(ct * 4 + 2) * 64 + l];
        const short8 A3 = wa[(ct * 4 + 3) * 64 + l];
        const float4 bv = *(const float4*)(g_bias + cbase + 4 * lh);
#pragma unroll
        for (int rg = 0; rg < 4; ++rg) {
            f32x4 acc = {bv.x, bv.y, bv.z, bv.w};
            acc = __builtin_amdgcn_mfma_f32_16x16x32_bf16(A0, Bf[rg][0], acc, 0, 0, 0);
            acc = __builtin_amdgcn_mfma_f32_16x16x32_bf16(A1, Bf[rg][1], acc, 0, 0, 0);
            acc = __builtin_amdgcn_mfma_f32_16x16x32_bf16(A2, Bf[rg][2], acc, 0, 0, 0);
            acc = __builtin_amdgcn_mfma_f32_16x16x32_bf16(A3, Bf[rg][3], acc, 0, 0, 0);
            u32 p0 = (u32)f2b(acc[0]) | ((u32)f2b(acc[1]) << 16);
            u32 p1 = (u32)f2b(acc[2]) | ((u32)f2b(acc[3]) << 16);
            uint2 pv; pv.x = p0; pv.y = p1;
            *(uint2*)(g_xg + (size_t)(m0 + rg * 16 + lr) * G_ + cbase + 4 * lh) = pv;
        }
    }
}

// ---------- K2: recurrence, TWO batches per block (512 thr, 8 waves, 2 waves/EU) ----------
// r13 change: grid 64 -> 32 blocks; each block runs batches (2b, 2b+1). The Whh
// weight registers are SHARED between the two recurrences (no register doubling,
// no occupancy change). Per barrier interval each wave processes b0 then b1 —
// independent dot blocks + independent ACT chains let the scheduler fill b0's
// ds_read/exp latency with b1's dots, and the fixed per-step tail (barrier skew,
// ds_read, exp chain) is amortized over 2 batch-steps. Per-batch math is
// instruction-identical to r12 -> absmax unchanged.
__global__ __launch_bounds__(512)
__attribute__((amdgpu_waves_per_eu(2, 2)))
void lstm_split(const void* __restrict__ h0, const void* __restrict__ c0) {
    const int mode = g_mode;
    const int t = threadIdx.x;
    const int b0 = blockIdx.x * 2;
    const int b1 = b0 + 1;
    const int u = t >> 1;
    const int half = t & 1;

    __shared__ __align__(16) u32 h8[2][2][H_ / 4];  // [batch][parity][64], 1 KB

    // --- 32 weight quads into named v4u via asm (validated pattern) ---
    v4u W00, W01, W02, W03, W04, W05, W06, W07, W08, W09, W10, W11, W12, W13, W14, W15;
    v4u W16, W17, W18, W19, W20, W21, W22, W23, W24, W25, W26, W27, W28, W29, W30, W31;
    {
        const u32* wp = g_Wi8 + (size_t)t * 128;   // = u*256 + half*128
        asm volatile(
            "global_load_dwordx4 %0, %16, off\n\t"
            "global_load_dwordx4 %1, %16, off offset:16\n\t"
            "global_load_dwordx4 %2, %16, off offset:32\n\t"
            "global_load_dwordx4 %3, %16, off offset:48\n\t"
            "global_load_dwordx4 %4, %16, off offset:64\n\t"
            "global_load_dwordx4 %5, %16, off offset:80\n\t"
            "global_load_dwordx4 %6, %16, off offset:96\n\t"
            "global_load_dwordx4 %7, %16, off offset:112\n\t"
            "global_load_dwordx4 %8, %16, off offset:128\n\t"
            "global_load_dwordx4 %9, %16, off offset:144\n\t"
            "global_load_dwordx4 %10, %16, off offset:160\n\t"
            "global_load_dwordx4 %11, %16, off offset:176\n\t"
            "global_load_dwordx4 %12, %16, off offset:192\n\t"
            "global_load_dwordx4 %13, %16, off offset:208\n\t"
            "global_load_dwordx4 %14, %16, off offset:224\n\t"
            "global_load_dwordx4 %15, %16, off offset:240\n\t"
            "s_waitcnt vmcnt(0)"
            : "=&v"(W00), "=&v"(W01), "=&v"(W02), "=&v"(W03),
              "=&v"(W04), "=&v"(W05), "=&v"(W06), "=&v"(W07),
              "=&v"(W08), "=&v"(W09), "=&v"(W10), "=&v"(W11),
              "=&v"(W12), "=&v"(W13), "=&v"(W14), "=&v"(W15)
            : "v"(wp));
        asm volatile(
            "global_load_dwordx4 %0, %16, off offset:256\n\t"
            "global_load_dwordx4 %1, %16, off offset:272\n\t"
            "global_load_dwordx4 %2, %16, off offset:288\n\t"
            "global_load_dwordx4 %3, %16, off offset:304\n\t"
            "global_load_dwordx4 %4, %16, off offset:320\n\t"
            "global_load_dwordx4 %5, %16, off offset:336\n\t"
            "global_load_dwordx4 %6, %16, off offset:352\n\t"
            "global_load_dwordx4 %7, %16, off offset:368\n\t"
            "global_load_dwordx4 %8, %16, off offset:384\n\t"
            "global_load_dwordx4 %9, %16, off offset:400\n\t"
            "global_load_dwordx4 %10, %16, off offset:416\n\t"
            "global_load_dwordx4 %11, %16, off offset:432\n\t"
            "global_load_dwordx4 %12, %16, off offset:448\n\t"
            "global_load_dwordx4 %13, %16, off offset:464\n\t"
            "global_load_dwordx4 %14, %16, off offset:480\n\t"
            "global_load_dwordx4 %15, %16, off offset:496\n\t"
            "s_waitcnt vmcnt(0)"
            : "=&v"(W16), "=&v"(W17), "=&v"(W18), "=&v"(W19),
              "=&v"(W20), "=&v"(W21), "=&v"(W22), "=&v"(W23),
              "=&v"(W24), "=&v"(W25), "=&v"(W26), "=&v"(W27),
              "=&v"(W28), "=&v"(W29), "=&v"(W30), "=&v"(W31)
            : "v"(wp));
    }

    const float4 wsc4 = *(const float4*)(g_wscale + 4 * u);
    float cr0 = 0.0f, cr1 = 0.0f;
    if (half == 0) {
        cr0 = ldin(mode, c0, (size_t)b0 * H_ + u);
        cr1 = ldin(mode, c0, (size_t)b1 * H_ + u);
    }

    if (t < 128) {                                   // pack h0 for both batches
        const int bi = t >> 6, tt = t & 63;
        u32 pk = 0;
#pragma unroll
        for (int i = 0; i < 4; ++i) {
            float h = ldin(mode, h0, (size_t)(b0 + bi) * H_ + 4 * tt + i);
            int q = (int)rintf(fminf(fmaxf(h, -1.0f), 1.0f) * 127.0f);
            pk |= ((u32)(q & 0xff)) << (8 * i);
        }
        h8[bi][0][tt] = pk;
    }
    const u16* xp0 = g_xg + (size_t)b0 * S_ * G_ + 4 * u;
    const u16* xp1 = g_xg + (size_t)b1 * S_ * G_ + 4 * u;
    float* hsp0 = g_hs + (size_t)b0 * S_ * H_ + u;
    float* hsp1 = g_hs + (size_t)b1 * S_ * H_ + u;

    // prime rolling prefetch buffers (distance 4, both batches)
    ushort4 xq0[4], xq1[4];
#pragma unroll
    for (int e = 0; e < 4; ++e) {
        xq0[e] = *(const ushort4*)(xp0 + (size_t)e * G_);
        xq1[e] = *(const ushort4*)(xp1 + (size_t)e * G_);
    }

    asm volatile("s_waitcnt lgkmcnt(0)\n\t"
                 "s_barrier" ::: "memory");

#define DOTG(HV, WA, WB, WC, WD)                                              \
            ai = dot4i8(HV.x, WA.x, ai); af = dot4i8(HV.x, WA.y, af);         \
            ag = dot4i8(HV.x, WA.z, ag); ao = dot4i8(HV.x, WA.w, ao);         \
            ai = dot4i8(HV.y, WB.x, ai); af = dot4i8(HV.y, WB.y, af);         \
            ag = dot4i8(HV.y, WB.z, ag); ao = dot4i8(HV.y, WB.w, ao);         \
            ai = dot4i8(HV.z, WC.x, ai); af = dot4i8(HV.z, WC.y, af);         \
            ag = dot4i8(HV.z, WC.z, ag); ao = dot4i8(HV.z, WC.w, ao);         \
            ai = dot4i8(HV.w, WD.x, ai); af = dot4i8(HV.w, WD.y, af);         \
            ag = dot4i8(HV.w, WD.z, ag); ao = dot4i8(HV.w, WD.w, ao);

    // one batch's step: dots + DPP combine + ACT + publish (no barrier)
#define BSTEP(BI, CREG, XQ, XP, HSP, E, S, SN)                                \
    {                                                                         \
        const uint4* hp = (const uint4*)h8[BI][(S) & 1] + half * 8;           \
        uint4 h0v = hp[0], h1v = hp[1], h2v = hp[2], h3v = hp[3];             \
        uint4 h4v = hp[4], h5v = hp[5], h6v = hp[6], h7v = hp[7];             \
        int ai = 0, af = 0, ag = 0, ao = 0;                                   \
        DOTG(h0v, W00, W01, W02, W03)                                         \
        DOTG(h1v, W04, W05, W06, W07)                                         \
        DOTG(h2v, W08, W09, W10, W11)                                         \
        DOTG(h3v, W12, W13, W14, W15)                                         \
        DOTG(h4v, W16, W17, W18, W19)                                         \
        DOTG(h5v, W20, W21, W22, W23)                                         \
        DOTG(h6v, W24, W25, W26, W27)                                         \
        DOTG(h7v, W28, W29, W30, W31)                                         \
        ai = dppadd1(ai);                                                     \
        af = dppadd1(af);                                                     \
        ag = dppadd1(ag);                                                     \
        ao = dppadd1(ao);                                                     \
        if (half == 0) {                                                      \
            const ushort4 xv = XQ[E];                                         \
            XQ[E] = *(const ushort4*)(XP + (size_t)(SN) * G_);                \
            float gi = (float)ai * wsc4.x + b2f(xv.x);                        \
            float gf = (float)af * wsc4.y + b2f(xv.y);                        \
            float gg = (float)ag * wsc4.z + b2f(xv.z);                        \
            float go = (float)ao * wsc4.w + b2f(xv.w);                        \
            float ii = fsig(gi);                                              \
            float ff = fsig(gf);                                              \
            float gv = ftanh(gg);                                             \
            float oo = fsig(go);                                              \
            CREG = fmaf(ff, CREG, ii * gv);                                   \
            float h = oo * ftanh(CREG);                                       \
            int q = (int)rintf(h * 127.0f) & 0xff;                            \
            ((u8*)h8[BI][((S) + 1) & 1])[u] = (u8)q;                          \
            HSP[(size_t)(S) * H_] = h;                                        \
        }                                                                     \
    }

    for (int s0 = 0; s0 < S_; s0 += 4) {
#pragma unroll
        for (int e = 0; e < 4; ++e) {
            const int s = s0 + e;
            const int sn = (s + 4 < S_) ? s + 4 : s;
            BSTEP(0, cr0, xq0, xp0, hsp0, e, s, sn)
            BSTEP(1, cr1, xq1, xp1, hsp1, e, s, sn)
            // LDS ordering only; global loads/stores stay in flight
            asm volatile("s_waitcnt lgkmcnt(0)\n\t"
                         "s_barrier" ::: "memory");
        }
    }
#undef BSTEP
#undef DOTG
}

// ---------- K3: output head — one wave per (s,b), fp32 h (precise math, unchanged) ----------
__global__ __launch_bounds__(256) void head_kernel(const void* __restrict__ Wout,
                                                   const void* __restrict__ bout,
                                                   void* __restrict__ yv) {
    const int mode = g_mode;
    const int t = threadIdx.x;
    const int idx = blockIdx.x * 4 + (t >> 6);   // (s,b) pair
    const int l = t & 63;
    const int s = idx >> 6, b = idx & 63;
    const float* hb = g_hs + ((size_t)b * S_ + s) * H_ + 4 * l;
    float4 hv = *(const float4*)hb;
    float p = hv.x * ldin(mode, Wout, 4 * l + 0)
            + hv.y * ldin(mode, Wout, 4 * l + 1)
            + hv.z * ldin(mode, Wout, 4 * l + 2)
            + hv.w * ldin(mode, Wout, 4 * l + 3);
#pragma unroll
    for (int off = 32; off > 0; off >>= 1) p += __shfl_down(p, off, 64);
    if (l == 0) {
        float yf = sigmoidf_(clamp30(p + ldin(mode, bout, 0)));
        if (mode) ((float*)yv)[(size_t)s * B_ + b] = yf;
        else      ((u16*)yv)[(size_t)s * B_ + b] = f2b(yf);
    }
}

extern "C" void kernel_launch(void* const* d_in, const int* in_sizes, int n_in,
                              void* d_out, int out_size, void* d_ws, size_t ws_size,
                              hipStream_t stream) {
    const void* pw   = d_in[0];   // [B,S,50]
    const void* Wemb = d_in[1];   // [E,50]
    const void* bemb = d_in[2];   // [E]
    const void* Wih  = d_in[3];   // [G,E]
    const void* Whh  = d_in[4];   // [G,H]
    const void* bih  = d_in[5];   // [G]
    const void* bhh  = d_in[6];   // [G]
    const void* Wout = d_in[7];   // [1,H]
    const void* bout = d_in[8];   // [1]
    const void* h0   = d_in[9];   // [B,H]
    const void* c0   = d_in[10];  // [B,H]
    void* y = d_out;              // [S,B]
    (void)d_ws; (void)ws_size;

    sniff_kernel<<<1, 1, 0, stream>>>((const u16*)Wemb);
    prep_wa<<<(E_ * G_) / 256, 256, 0, stream>>>(Wih);
    prep_wi8<<<G_ / 256, 256, 0, stream>>>(Whh, bih, bhh);
    xg_mfma<<<(B_ * S_) / 64, 256, 0, stream>>>(pw, Wemb, bemb);
    lstm_split<<<B_ / 2, 512, 0, stream>>>(h0, c0);
    head_kernel<<<(S_ * B_) / 4, 256, 0, stream>>>(Wout, bout, y);
}

// Round 14
// 2091.443 us; speedup vs baseline: 2.0438x; 2.0438x over previous
//
#include <hip/hip_runtime.h>
#include <hip/hip_bf16.h>

// B=64, S=2048, WIN=50, E=128, H=256, G=4H=1024.
#define B_ 64
#define S_ 2048
#define W_ 50
#define E_ 128
#define H_ 256
#define G_ 1024

typedef unsigned short u16;
typedef unsigned int u32;
typedef unsigned char u8;
typedef unsigned int v4u __attribute__((ext_vector_type(4)));
typedef __attribute__((ext_vector_type(8))) short short8;   // bf16x8 MFMA frag
typedef __attribute__((ext_vector_type(4))) float f32x4;    // MFMA acc

// Module-global scratch (BSS; d_ws untrusted).
__device__ int g_mode;                          // 0 = bf16 buffers, 1 = fp32 buffers
__device__ u16 g_WA[E_ * G_];                   // Wih in MFMA A-frag order (bf16) [r3-validated]
__device__ float g_bias[G_];                    // bih+bhh, gate-interleaved c = 4u+q
__device__ u32 g_Wi8[G_ * 64];                  // [u][j][g]: pack4(Whh col c=4u+g, k=4j..4j+3)
__device__ float g_wscale[G_];                  // per-column dequant: max|W[:,c]| /(127*127), c=4u+g
__device__ u16 g_xg[(size_t)B_ * S_ * G_];      // [b][s][1024] bf16, biases folded (validated)
__device__ float g_hs[(size_t)B_ * S_ * H_];    // [b][s][u] fp32 hidden states (for output head)

__device__ __forceinline__ float b2f(u16 u) {
    union { u32 i; float f; } v;
    v.i = ((u32)u) << 16;
    return v.f;
}
__device__ __forceinline__ u16 f2b(float f) {
    __hip_bfloat16 h = __float2bfloat16(f);
    return *reinterpret_cast<u16*>(&h);
}
__device__ __forceinline__ float ldin(int mode, const void* p, size_t i) {
    return mode ? ((const float*)p)[i] : b2f(((const u16*)p)[i]);
}
__device__ __forceinline__ float clamp30(float x) {
    return fminf(fmaxf(x, -30.0f), 30.0f);
}
__device__ __forceinline__ float sigmoidf_(float x) { return 1.0f / (1.0f + __expf(-x)); }
__device__ __forceinline__ float tanhf_(float x) {
    float e = __expf(2.0f * x);
    return 1.0f - 2.0f / (e + 1.0f);
}
// Fast forms for the lstm hot loop ONLY (r10-validated): v_rcp_f32 (<=1 ulp)
// replaces the IEEE divide chain; rcp(inf)=0 gives exact saturation -> no clamp.
__device__ __forceinline__ float fastrcp(float x) {
    float r;
    asm("v_rcp_f32 %0, %1" : "=v"(r) : "v"(x));
    return r;
}
__device__ __forceinline__ float fsig(float x) { return fastrcp(1.0f + __expf(-x)); }
__device__ __forceinline__ float ftanh(float x) {
    return fmaf(-2.0f, fastrcp(1.0f + __expf(2.0f * x)), 1.0f);
}
// r11-validated: lane^1 pair-combine as VALU DPP (quad_perm [1,0,3,2] = 0xB1).
__device__ __forceinline__ int dppadd1(int x) {
    return x + __builtin_amdgcn_update_dpp(0, x, 0xB1, 0xF, 0xF, true);
}
__device__ __forceinline__ int dot4i8(u32 a, u32 b, int acc) {
#if __has_builtin(__builtin_amdgcn_sdot4)
    return __builtin_amdgcn_sdot4(a, b, acc, false);
#else
    acc += (int)(signed char)(a)       * (int)(signed char)(b);
    acc += (int)(signed char)(a >> 8)  * (int)(signed char)(b >> 8);
    acc += (int)(signed char)(a >> 16) * (int)(signed char)(b >> 16);
    acc += (int)(signed char)(a >> 24) * (int)(signed char)(b >> 24);
    return acc;
#endif
}

// ---------- K0: dtype sniffer (validated) ----------
__global__ void sniff_kernel(const u16* __restrict__ wemb) {
    int sane = 0;
    for (int i = 0; i < 2048; ++i) {
        int ex = (wemb[i] >> 7) & 0xFF;
        if (ex == 0 || (ex >= 96 && ex <= 143)) ++sane;
    }
    g_mode = (sane >= 1900) ? 0 : 1;
}

// ---------- K0b: Wih -> MFMA A-fragment order (r3-validated) ----------
__global__ __launch_bounds__(256) void prep_wa(const void* __restrict__ src) {
    const int mode = g_mode;
    int i = blockIdx.x * 256 + threadIdx.x;          // dst flat index, 0..131071
    int j = i & 7, l = (i >> 3) & 63, ks = (i >> 9) & 3, ct = i >> 11;
    int c = ct * 16 + (l & 15);
    int e = ks * 32 + (l >> 4) * 8 + j;
    int row = ((c & 3) << 8) + (c >> 2);
    g_WA[i] = f2b(ldin(mode, src, (size_t)row * E_ + e));
}

// ---------- K0c: Whh -> int8, unit-major quad layout [u][j][g]; + gate biases ----------
__global__ __launch_bounds__(256) void prep_wi8(const void* __restrict__ src,
                                                const void* __restrict__ bih,
                                                const void* __restrict__ bhh) {
    const int mode = g_mode;
    int c = blockIdx.x * 256 + threadIdx.x;          // c = 4u+g, 0..1023
    int row = ((c & 3) << 8) + (c >> 2);             // gate*256 + unit (validated)
    g_bias[c] = ldin(mode, bih, row) + ldin(mode, bhh, row);
    const size_t base = (size_t)row * H_;
    float m = 0.0f;
    for (int k = 0; k < H_; ++k) m = fmaxf(m, fabsf(ldin(mode, src, base + k)));
    float inv = (m > 0.0f) ? 127.0f / m : 0.0f;
    g_wscale[c] = m / (127.0f * 127.0f);             // w-scale * h-scale(1/127)
    for (int j = 0; j < 64; ++j) {
        u32 pk = 0;
#pragma unroll
        for (int i = 0; i < 4; ++i) {
            int q = (int)rintf(ldin(mode, src, base + 4 * j + i) * inv);
            q = max(-127, min(127, q));
            pk |= ((u32)(q & 0xff)) << (8 * i);
        }
        g_Wi8[(size_t)(c >> 2) * 256 + j * 4 + (c & 3)] = pk;
    }
}

// ---------- K1: fused embedding + input projection (MFMA, 64-row blocks, r9-validated) ----------
__global__ __launch_bounds__(256) void xg_mfma(const void* __restrict__ pw,
                                               const void* __restrict__ Wemb,
                                               const void* __restrict__ bemb) {
    const int mode = g_mode;
    const int t = threadIdx.x;
    const int m0 = blockIdx.x * 64;
    __shared__ float pwS[64][W_ + 2];                // 13.3 KB
    __shared__ float Wl[E_ * 51];                    // 26 KB
    __shared__ __align__(16) u16 embL[64][136];      // 17.4 KB   (total ~56.7 KB)

    for (int i = t; i < E_ * W_; i += 256) {
        int e = i / W_, w = i - e * W_;
        Wl[e * 51 + w] = ldin(mode, Wemb, i);
    }
    for (int i = t; i < 64 * W_; i += 256) {
        int r = i / W_, w = i - r * W_;
        pwS[r][w] = ldin(mode, pw, (size_t)(m0 + r) * W_ + w);
    }
    __syncthreads();

    {   // emb: e = t&127 constant per thread; W-row cached in regs (r8-validated)
        const int e = t & 127;
        float wreg[W_];
#pragma unroll
        for (int w = 0; w < W_; ++w) wreg[w] = Wl[e * 51 + w];
        const float bb = ldin(mode, bemb, e);
#pragma unroll
        for (int i = 0; i < 32; ++i) {
            const int r = i * 2 + (t >> 7);          // covers all 64 rows x 128 cols
            float a = bb;
#pragma unroll
            for (int w = 0; w < W_; ++w) a = fmaf(pwS[r][w], wreg[w], a);
            embL[r][e] = f2b(fmaxf(a, 0.0f));
        }
    }
    __syncthreads();

    const int l = t & 63;
    const int wv = t >> 6;                           // wave id 0..3 -> 256 c-cols each
    const int lr = l & 15;                           // B-col / D-col within tile
    const int lh = l >> 4;
    short8 Bf[4][4];
#pragma unroll
    for (int rg = 0; rg < 4; ++rg)
#pragma unroll
        for (int ks = 0; ks < 4; ++ks)
            Bf[rg][ks] = *(const short8*)&embL[rg * 16 + lr][ks * 32 + lh * 8];

    const short8* wa = (const short8*)g_WA;
#pragma unroll 2
    for (int tt = 0; tt < 16; ++tt) {
        const int ct = wv * 16 + tt;                 // c-tile index 0..63
        const int cbase = ct * 16;
        const short8 A0 = wa[(ct * 4 + 0) * 64 + l];
        const short8 A1 = wa[(ct * 4 + 1) * 64 + l];
        const short8 A2 = wa[(ct * 4 + 2) * 64 + l];
        const short8 A3 = wa[(ct * 4 + 3) * 64 + l];
        const float4 bv = *(const float4*)(g_bias + cbase + 4 * lh);
#pragma unroll
        for (int rg = 0; rg < 4; ++rg) {
            f32x4 acc = {bv.x, bv.y, bv.z, bv.w};
            acc = __builtin_amdgcn_mfma_f32_16x16x32_bf16(A0, Bf[rg][0], acc, 0, 0, 0);
            acc = __builtin_amdgcn_mfma_f32_16x16x32_bf16(A1, Bf[rg][1], acc, 0, 0, 0);
            acc = __builtin_amdgcn_mfma_f32_16x16x32_bf16(A2, Bf[rg][2], acc, 0, 0, 0);
            acc = __builtin_amdgcn_mfma_f32_16x16x32_bf16(A3, Bf[rg][3], acc, 0, 0, 0);
            u32 p0 = (u32)f2b(acc[0]) | ((u32)f2b(acc[1]) << 16);
            u32 p1 = (u32)f2b(acc[2]) | ((u32)f2b(acc[3]) << 16);
            uint2 pv; pv.x = p0; pv.y = p1;
            *(uint2*)(g_xg + (size_t)(m0 + rg * 16 + lr) * G_ + cbase + 4 * lh) = pv;
        }
    }
}

// ---------- K2: recurrence, split-K pairs (512 thr, 8 waves, 2 waves/EU) ----------
// r12-VALIDATED VERBATIM (1692us): r3 skeleton + rcp-ACT (r10) + DPP pair-combine
// and clamp-free h-quant (r11/r12). Best measured configuration; r13's 2-batch
// ILP variant refuted (regalloc would not interleave the two dependent chains).
__global__ __launch_bounds__(512)
__attribute__((amdgpu_waves_per_eu(2, 2)))
void lstm_split(const void* __restrict__ h0, const void* __restrict__ c0) {
    const int mode = g_mode;
    const int t = threadIdx.x;
    const int b = blockIdx.x;
    const int u = t >> 1;
    const int half = t & 1;

    __shared__ __align__(16) u32 h8[2][H_ / 4];  // double-buffered h (i8), 2x256 B

    // --- 32 weight quads into named v4u via asm (validated pattern, waitcnt per block) ---
    v4u W00, W01, W02, W03, W04, W05, W06, W07, W08, W09, W10, W11, W12, W13, W14, W15;
    v4u W16, W17, W18, W19, W20, W21, W22, W23, W24, W25, W26, W27, W28, W29, W30, W31;
    {
        const u32* wp = g_Wi8 + (size_t)t * 128;   // = u*256 + half*128
        asm volatile(
            "global_load_dwordx4 %0, %16, off\n\t"
            "global_load_dwordx4 %1, %16, off offset:16\n\t"
            "global_load_dwordx4 %2, %16, off offset:32\n\t"
            "global_load_dwordx4 %3, %16, off offset:48\n\t"
            "global_load_dwordx4 %4, %16, off offset:64\n\t"
            "global_load_dwordx4 %5, %16, off offset:80\n\t"
            "global_load_dwordx4 %6, %16, off offset:96\n\t"
            "global_load_dwordx4 %7, %16, off offset:112\n\t"
            "global_load_dwordx4 %8, %16, off offset:128\n\t"
            "global_load_dwordx4 %9, %16, off offset:144\n\t"
            "global_load_dwordx4 %10, %16, off offset:160\n\t"
            "global_load_dwordx4 %11, %16, off offset:176\n\t"
            "global_load_dwordx4 %12, %16, off offset:192\n\t"
            "global_load_dwordx4 %13, %16, off offset:208\n\t"
            "global_load_dwordx4 %14, %16, off offset:224\n\t"
            "global_load_dwordx4 %15, %16, off offset:240\n\t"
            "s_waitcnt vmcnt(0)"
            : "=&v"(W00), "=&v"(W01), "=&v"(W02), "=&v"(W03),
              "=&v"(W04), "=&v"(W05), "=&v"(W06), "=&v"(W07),
              "=&v"(W08), "=&v"(W09), "=&v"(W10), "=&v"(W11),
              "=&v"(W12), "=&v"(W13), "=&v"(W14), "=&v"(W15)
            : "v"(wp));
        asm volatile(
            "global_load_dwordx4 %0, %16, off offset:256\n\t"
            "global_load_dwordx4 %1, %16, off offset:272\n\t"
            "global_load_dwordx4 %2, %16, off offset:288\n\t"
            "global_load_dwordx4 %3, %16, off offset:304\n\t"
            "global_load_dwordx4 %4, %16, off offset:320\n\t"
            "global_load_dwordx4 %5, %16, off offset:336\n\t"
            "global_load_dwordx4 %6, %16, off offset:352\n\t"
            "global_load_dwordx4 %7, %16, off offset:368\n\t"
            "global_load_dwordx4 %8, %16, off offset:384\n\t"
            "global_load_dwordx4 %9, %16, off offset:400\n\t"
            "global_load_dwordx4 %10, %16, off offset:416\n\t"
            "global_load_dwordx4 %11, %16, off offset:432\n\t"
            "global_load_dwordx4 %12, %16, off offset:448\n\t"
            "global_load_dwordx4 %13, %16, off offset:464\n\t"
            "global_load_dwordx4 %14, %16, off offset:480\n\t"
            "global_load_dwordx4 %15, %16, off offset:496\n\t"
            "s_waitcnt vmcnt(0)"
            : "=&v"(W16), "=&v"(W17), "=&v"(W18), "=&v"(W19),
              "=&v"(W20), "=&v"(W21), "=&v"(W22), "=&v"(W23),
              "=&v"(W24), "=&v"(W25), "=&v"(W26), "=&v"(W27),
              "=&v"(W28), "=&v"(W29), "=&v"(W30), "=&v"(W31)
            : "v"(wp));
    }

    const float4 wsc4 = *(const float4*)(g_wscale + 4 * u);
    float c_reg = (half == 0) ? ldin(mode, c0, (size_t)b * H_ + u) : 0.0f;

    if (t < H_ / 4) {
        u32 pk = 0;
#pragma unroll
        for (int i = 0; i < 4; ++i) {
            float h = ldin(mode, h0, (size_t)b * H_ + 4 * t + i);
            int q = (int)rintf(fminf(fmaxf(h, -1.0f), 1.0f) * 127.0f);
            pk |= ((u32)(q & 0xff)) << (8 * i);
        }
        h8[0][t] = pk;
    }
    const u16* xp = g_xg + (size_t)b * S_ * G_ + 4 * u;
    float* hsp = g_hs + (size_t)b * S_ * H_ + u;

    // prime rolling prefetch buffer (all lanes load; odd lanes' copies unused but
    // same cache lines -> no extra traffic, no divergence)
    ushort4 xq[4];
#pragma unroll
    for (int e = 0; e < 4; ++e)
        xq[e] = *(const ushort4*)(xp + (size_t)e * G_);

    asm volatile("s_waitcnt lgkmcnt(0)\n\t"
                 "s_barrier" ::: "memory");

#define DOTG(HV, WA, WB, WC, WD)                                              \
            ai = dot4i8(HV.x, WA.x, ai); af = dot4i8(HV.x, WA.y, af);         \
            ag = dot4i8(HV.x, WA.z, ag); ao = dot4i8(HV.x, WA.w, ao);         \
            ai = dot4i8(HV.y, WB.x, ai); af = dot4i8(HV.y, WB.y, af);         \
            ag = dot4i8(HV.y, WB.z, ag); ao = dot4i8(HV.y, WB.w, ao);         \
            ai = dot4i8(HV.z, WC.x, ai); af = dot4i8(HV.z, WC.y, af);         \
            ag = dot4i8(HV.z, WC.z, ag); ao = dot4i8(HV.z, WC.w, ao);         \
            ai = dot4i8(HV.w, WD.x, ai); af = dot4i8(HV.w, WD.y, af);         \
            ag = dot4i8(HV.w, WD.z, ag); ao = dot4i8(HV.w, WD.w, ao);

    for (int s0 = 0; s0 < S_; s0 += 4) {
#pragma unroll
        for (int e = 0; e < 4; ++e) {
            const int s = s0 + e;
            // consume current xq, immediately re-issue for s+4 (rolling prefetch)
            const ushort4 xv = xq[e];
            const int sn = (s + 4 < S_) ? s + 4 : s;
            xq[e] = *(const ushort4*)(xp + (size_t)sn * G_);

            const uint4* hp = (const uint4*)h8[s & 1] + half * 8;
            uint4 h0v = hp[0], h1v = hp[1], h2v = hp[2], h3v = hp[3];
            uint4 h4v = hp[4], h5v = hp[5], h6v = hp[6], h7v = hp[7];

            int ai = 0, af = 0, ag = 0, ao = 0;
            DOTG(h0v, W00, W01, W02, W03)
            DOTG(h1v, W04, W05, W06, W07)
            DOTG(h2v, W08, W09, W10, W11)
            DOTG(h3v, W12, W13, W14, W15)
            DOTG(h4v, W16, W17, W18, W19)
            DOTG(h5v, W20, W21, W22, W23)
            DOTG(h6v, W24, W25, W26, W27)
            DOTG(h7v, W28, W29, W30, W31)

            ai = dppadd1(ai);
            af = dppadd1(af);
            ag = dppadd1(ag);
            ao = dppadd1(ao);

            if (half == 0) {
                float gi = (float)ai * wsc4.x + b2f(xv.x);
                float gf = (float)af * wsc4.y + b2f(xv.y);
                float gg = (float)ag * wsc4.z + b2f(xv.z);
                float go = (float)ao * wsc4.w + b2f(xv.w);
                float ii = fsig(gi);
                float ff = fsig(gf);
                float gv = ftanh(gg);
                float oo = fsig(go);
                c_reg = fmaf(ff, c_reg, ii * gv);
                float h = oo * ftanh(c_reg);
                int q = (int)rintf(h * 127.0f) & 0xff;   // |h|<=1+2e-7 -> in range
                ((u8*)h8[(s + 1) & 1])[u] = (u8)q;   // single-byte publish
                hsp[(size_t)s * H_] = h;             // fire-and-forget
            }
            // LDS ordering only; global loads/stores stay in flight
            asm volatile("s_waitcnt lgkmcnt(0)\n\t"
                         "s_barrier" ::: "memory");
        }
    }
#undef DOTG
}

// ---------- K3: output head — one wave per (s,b), fp32 h (precise math, unchanged) ----------
__global__ __launch_bounds__(256) void head_kernel(const void* __restrict__ Wout,
                                                   const void* __restrict__ bout,
                                                   void* __restrict__ yv) {
    const int mode = g_mode;
    const int t = threadIdx.x;
    const int idx = blockIdx.x * 4 + (t >> 6);   // (s,b) pair
    const int l = t & 63;
    const int s = idx >> 6, b = idx & 63;
    const float* hb = g_hs + ((size_t)b * S_ + s) * H_ + 4 * l;
    float4 hv = *(const float4*)hb;
    float p = hv.x * ldin(mode, Wout, 4 * l + 0)
            + hv.y * ldin(mode, Wout, 4 * l + 1)
            + hv.z * ldin(mode, Wout, 4 * l + 2)
            + hv.w * ldin(mode, Wout, 4 * l + 3);
#pragma unroll
    for (int off = 32; off > 0; off >>= 1) p += __shfl_down(p, off, 64);
    if (l == 0) {
        float yf = sigmoidf_(clamp30(p + ldin(mode, bout, 0)));
        if (mode) ((float*)yv)[(size_t)s * B_ + b] = yf;
        else      ((u16*)yv)[(size_t)s * B_ + b] = f2b(yf);
    }
}

extern "C" void kernel_launch(void* const* d_in, const int* in_sizes, int n_in,
                              void* d_out, int out_size, void* d_ws, size_t ws_size,
                              hipStream_t stream) {
    const void* pw   = d_in[0];   // [B,S,50]
    const void* Wemb = d_in[1];   // [E,50]
    const void* bemb = d_in[2];   // [E]
    const void* Wih  = d_in[3];   // [G,E]
    const void* Whh  = d_in[4];   // [G,H]
    const void* bih  = d_in[5];   // [G]
    const void* bhh  = d_in[6];   // [G]
    const void* Wout = d_in[7];   // [1,H]
    const void* bout = d_in[8];   // [1]
    const void* h0   = d_in[9];   // [B,H]
    const void* c0   = d_in[10];  // [B,H]
    void* y = d_out;              // [S,B]
    (void)d_ws; (void)ws_size;

    sniff_kernel<<<1, 1, 0, stream>>>((const u16*)Wemb);
    prep_wa<<<(E_ * G_) / 256, 256, 0, stream>>>(Wih);
    prep_wi8<<<G_ / 256, 256, 0, stream>>>(Whh, bih, bhh);
    xg_mfma<<<(B_ * S_) / 64, 256, 0, stream>>>(pw, Wemb, bemb);
    lstm_split<<<B_, 512, 0, stream>>>(h0, c0);
    head_kernel<<<(S_ * B_) / 4, 256, 0, stream>>>(Wout, bout, y);
}